// Round 8
// baseline (3269.770 us; speedup 1.0000x reference)
//
#include <hip/hip_runtime.h>
#include <hip/hip_bf16.h>
#include <math.h>

// Problem constants
#define Bz 32
#define Nn 128
#define Hh 256
#define Dd 256
#define Ff 512
#define Gg 768
#define NT 1024         // 16 waves per block; 256 blocks = 32 batches x 8 col-slices

typedef short v8s __attribute__((ext_vector_type(8)));   // 8 bf16
typedef float f4  __attribute__((ext_vector_type(4)));   // MFMA C/D
#define MFMA(a,b,c) __builtin_amdgcn_mfma_f32_16x16x32_bf16(a,b,c,0,0,0)

// Workspace layout (float elements)
#define WS_H0    0                          // [B][256]
#define WS_GH0   (WS_H0 + Bz*Hh)            // [B][768]  h0@Wh + bh
#define WS_ZW1   (WS_GH0 + Bz*Gg)           // [B][512]  z@W1c
#define WS_GXP   (WS_ZW1 + Bz*Ff)           // [B][2][8][768] gx1 partials (parity)
#define WS_LOGP  (WS_GXP + Bz*2*8*Gg)       // [B][2][8][128] logit partials (parity)
#define WS_BAR   (WS_LOGP + Bz*2*8*Nn)      // [B][32] barrier counters
#define WS_XS    (WS_BAR + Bz*32)           // [B][2][8mt][8ks][128 u64] state exchange
#define WS_WB    (WS_XS + Bz*32768)         // [160][8][64][4] uint B-frag packed weights

// LDS layout (bytes) — total 163648 <= 163840
#define SM_SW    0         // [10 lt][8 ks][64 lane] uint4 : 6 Wh + 4 W1b tiles (81920)
#define SM_SST   81920     // ushort[8mt][8ks][512] bf16 state mirror (65536)
#define SM_NLDS  147456    // ushort[8mt][512] new-state own-slice staging (8192)
#define SM_GXF   155648    // float[768] full gx1 (unscaled pooled-sum @ Wx)
#define SM_HPF   158720    // ushort[256] h_prov bf16
#define SM_GX2   159232    // float[96]
#define SM_GHT   159616    // float[96]  hp @ Wh (own gate cols)
#define SM_BASE  160000    // float[64]
#define SM_BHS   160256    // float[96]
#define SM_PSN   160640    // float[32]
#define SM_LOGI  160768    // float[128]
#define SM_TGR   161280    // uchar[2 par][128] teacher row (prefetched)
#define SM_RBIT  161536    // uint[2 par][4]
#define SM_ANCW  161568    // uint[2 par][4]
#define SM_AMASK 161600    // uint[128][4]
#define SMEM_SZ  163648

__device__ __forceinline__ unsigned short f2bf(float x) {
  unsigned u = __float_as_uint(x);
  u = u + 0x7fffu + ((u >> 16) & 1u);   // RNE
  return (unsigned short)(u >> 16);
}
__device__ __forceinline__ unsigned pack2(float e, float o) {
  return (unsigned)f2bf(e) | ((unsigned)f2bf(o) << 16);
}
__device__ __forceinline__ unsigned pkbf(float x, float y) {
  __hip_bfloat162 h = __float22bfloat162_rn(make_float2(x, y));
  union { __hip_bfloat162 h; unsigned u; } c; c.h = h; return c.u;
}
__device__ __forceinline__ float bf2f(unsigned short s) {
  return __uint_as_float(((unsigned)s) << 16);
}
__device__ __forceinline__ float sigm(float x) { return 1.0f / (1.0f + __expf(-x)); }
__device__ __forceinline__ float tanh_fast(float x) { return 2.0f / (1.0f + __expf(-2.0f*x)) - 1.0f; }
__device__ __forceinline__ v8s u4v(uint4 q) { union { uint4 q; v8s v; } c; c.q = q; return c.v; }

// Relaxed AGENT atomics
__device__ __forceinline__ void ast32(unsigned* p, unsigned v) {
  __hip_atomic_store(p, v, __ATOMIC_RELAXED, __HIP_MEMORY_SCOPE_AGENT);
}
__device__ __forceinline__ unsigned ald32(const unsigned* p) {
  return __hip_atomic_load(p, __ATOMIC_RELAXED, __HIP_MEMORY_SCOPE_AGENT);
}
__device__ __forceinline__ void ast64(unsigned long long* p, unsigned long long v) {
  __hip_atomic_store(p, v, __ATOMIC_RELAXED, __HIP_MEMORY_SCOPE_AGENT);
}
__device__ __forceinline__ unsigned long long ald64(const unsigned long long* p) {
  return __hip_atomic_load(p, __ATOMIC_RELAXED, __HIP_MEMORY_SCOPE_AGENT);
}

// per-batch barrier among 8 blocks (R2-proven: single-thread poll + s_sleep)
__device__ __forceinline__ void bbar(unsigned* cnt, unsigned& seq)
{
  __builtin_amdgcn_s_waitcnt(0x0F70);   // vmcnt(0): this thread's stores complete
  __syncthreads();
  seq += 8;
  if (threadIdx.x == 0) {
    __hip_atomic_fetch_add(cnt, 1u, __ATOMIC_RELAXED, __HIP_MEMORY_SCOPE_AGENT);
    while (__hip_atomic_load(cnt, __ATOMIC_RELAXED, __HIP_MEMORY_SCOPE_AGENT) < seq)
      __builtin_amdgcn_s_sleep(1);
  }
  __syncthreads();
}

// ---------- prep 1 ----------
__global__ void __launch_bounds__(256) prep_init(
    const int* __restrict__ tg, const float* __restrict__ Wx,
    const float* __restrict__ Wh, const float* __restrict__ W1,
    float* __restrict__ ws, float* __restrict__ out)
{
  const int stride = gridDim.x * blockDim.x;
  const int t0 = blockIdx.x * blockDim.x + threadIdx.x;

  for (int i = t0; i < Bz*Nn*Nn; i += stride) {         // L = tril(targets, -1)
    int col = i & (Nn-1), row = (i >> 7) & (Nn-1);
    out[i] = (col < row) ? (float)tg[i] : 0.0f;
  }
  for (int i = t0; i < Bz; i += stride) out[Bz*Nn*Nn + i] = 0.0f;

  unsigned* BARu = (unsigned*)(ws + WS_BAR);
  for (int i = t0; i < Bz*32; i += stride) BARu[i] = 0u;

  // B-frag packing: regions [0,48) Wh | [48,80) W1b | [80,128) Wx | [128,160) W1a
  unsigned* Wb = (unsigned*)(ws + WS_WB);
  for (int i = t0; i < 160*2048; i += stride) {
    int jw = i & 3, l = (i >> 2) & 63, ks = (i >> 8) & 7, nt = i >> 11;
    int k = ks*32 + (l >> 4)*8 + 2*jw;
    int n16 = l & 15;
    float lo, hi;
    if (nt < 48)       { int c = nt*16 + n16;        lo = Wh[k*Gg + c];      hi = Wh[(k+1)*Gg + c]; }
    else if (nt < 80)  { int f = (nt-48)*16 + n16;   lo = W1[(Hh+k)*Ff + f]; hi = W1[(Hh+k+1)*Ff + f]; }
    else if (nt < 128) { int c = (nt-80)*16 + n16;   lo = Wx[k*Gg + c];      hi = Wx[(k+1)*Gg + c]; }
    else               { int f = (nt-128)*16 + n16;  lo = W1[k*Ff + f];      hi = W1[(k+1)*Ff + f]; }
    Wb[i] = pack2(lo, hi);
  }
}

// ---------- prep 2 ----------
__global__ void __launch_bounds__(256) prep_batch(
    const float* __restrict__ z, const float* __restrict__ Wi,
    const float* __restrict__ bi, const float* __restrict__ Wh,
    const float* __restrict__ bh, const float* __restrict__ W1,
    float* __restrict__ ws)
{
  const int b = blockIdx.x, tid = threadIdx.x;
  __shared__ float zs[Dd], h0s[Hh];
  zs[tid] = z[b*Dd + tid];
  __syncthreads();
  float acc = bi[tid];
  for (int d = 0; d < Dd; ++d) acc = fmaf(zs[d], Wi[d*Hh + tid], acc);
  const float h0 = tanhf(acc);
  h0s[tid] = h0;
  ws[WS_H0 + b*Hh + tid] = h0;
  __syncthreads();
  for (int g = tid; g < Gg; g += 256) {
    float a = bh[g];
    for (int h = 0; h < Hh; ++h) a = fmaf(h0s[h], Wh[h*Gg + g], a);
    ws[WS_GH0 + b*Gg + g] = a;
  }
  for (int f = tid; f < Ff; f += 256) {
    float a = 0.0f;
    for (int d = 0; d < Dd; ++d) a = fmaf(zs[d], W1[(2*Hh + d)*Ff + f], a);
    ws[WS_ZW1 + b*Ff + f] = a;
  }
}

// big-GEMM jobs (A from LDS mirror, B from LDS weight tiles)
__device__ __forceinline__ void G_mfma(const unsigned short* SST, const uint4* SW4,
    int mt0, bool do1, int lane, f4* acc)
{
  #pragma unroll
  for (int ks = 0; ks < 8; ++ks) {
    const v8s a0 = *(const v8s*)(SST + (mt0*8 + ks)*512 + lane*8);
    const v8s w0 = u4v(SW4[(0*8 + ks)*64 + lane]);
    const v8s w1 = u4v(SW4[(1*8 + ks)*64 + lane]);
    const v8s w2 = u4v(SW4[(2*8 + ks)*64 + lane]);
    const v8s w3 = u4v(SW4[(3*8 + ks)*64 + lane]);
    const v8s w4 = u4v(SW4[(4*8 + ks)*64 + lane]);
    const v8s w5 = u4v(SW4[(5*8 + ks)*64 + lane]);
    acc[0] = MFMA(a0,w0,acc[0]); acc[1] = MFMA(a0,w1,acc[1]);
    acc[2] = MFMA(a0,w2,acc[2]); acc[3] = MFMA(a0,w3,acc[3]);
    acc[4] = MFMA(a0,w4,acc[4]); acc[5] = MFMA(a0,w5,acc[5]);
    if (do1) {
      const v8s a1 = *(const v8s*)(SST + ((mt0+1)*8 + ks)*512 + lane*8);
      acc[6]  = MFMA(a1,w0,acc[6]);  acc[7]  = MFMA(a1,w1,acc[7]);
      acc[8]  = MFMA(a1,w2,acc[8]);  acc[9]  = MFMA(a1,w3,acc[9]);
      acc[10] = MFMA(a1,w4,acc[10]); acc[11] = MFMA(a1,w5,acc[11]);
    }
  }
}

__device__ __forceinline__ void G_epi(const f4* ac, int mt, int t, int r,
    int quad, int c16, int lane, const float* GX2, const float* BHS,
    const unsigned short* SST, unsigned short* NLDS, float* PSN)
{
  #pragma unroll
  for (int ct = 0; ct < 2; ++ct) {
    const int hcl = ct*16 + c16;
    const f4 cr = ac[0 + ct], cu = ac[2 + ct], cn = ac[4 + ct];
    const float gxr = GX2[hcl], gxu = GX2[32+hcl], gxn = GX2[64+hcl];
    const float bhr = BHS[hcl], bhu = BHS[32+hcl], bhn = BHS[64+hcl];
    float colsum = 0.0f;
    #pragma unroll
    for (int rg = 0; rg < 4; ++rg) {
      const int row = mt*16 + quad*4 + rg;
      if (row < t) {
        const int spi = ((hcl>>3)*16 + quad*4 + rg)*8 + (hcl & 7);
        const float old = bf2f(SST[(mt*8 + r)*512 + spi]);
        const float rv = sigm(gxr + cr[rg] + bhr);
        const float uv = sigm(gxu + cu[rg] + bhu);
        const float nv = tanh_fast(gxn + rv*(cn[rg] + bhn));
        const float ns = (1.0f-uv)*nv + uv*old;
        NLDS[mt*512 + spi] = f2bf(ns);
        colsum += ns;
      }
    }
    colsum += __shfl_down(colsum, 16);
    colsum += __shfl_down(colsum, 32);
    if (lane < 16) atomicAdd(&PSN[ct*16 + lane], colsum);
  }
}

__device__ __forceinline__ void L_mfma(const unsigned short* SST, const uint4* SW4,
    int mt0, bool do1, int lane, f4* acc)
{
  #pragma unroll
  for (int ks = 0; ks < 8; ++ks) {
    const v8s a0 = *(const v8s*)(SST + (mt0*8 + ks)*512 + lane*8);
    const v8s c0 = u4v(SW4[(6*8 + ks)*64 + lane]);
    const v8s c1 = u4v(SW4[(7*8 + ks)*64 + lane]);
    const v8s c2 = u4v(SW4[(8*8 + ks)*64 + lane]);
    const v8s c3 = u4v(SW4[(9*8 + ks)*64 + lane]);
    acc[0] = MFMA(a0,c0,acc[0]); acc[1] = MFMA(a0,c1,acc[1]);
    acc[2] = MFMA(a0,c2,acc[2]); acc[3] = MFMA(a0,c3,acc[3]);
    if (do1) {
      const v8s a1 = *(const v8s*)(SST + ((mt0+1)*8 + ks)*512 + lane*8);
      acc[4] = MFMA(a1,c0,acc[4]); acc[5] = MFMA(a1,c1,acc[5]);
      acc[6] = MFMA(a1,c2,acc[6]); acc[7] = MFMA(a1,c3,acc[7]);
    }
  }
}

__device__ __forceinline__ void L_epi(const f4* ac, int mt, int t,
    int quad, int c16, const float* BASE, const float* w2r, float* LOGI)
{
  #pragma unroll
  for (int rg = 0; rg < 4; ++rg) {
    float v = fmaxf(ac[0][rg] + BASE[c16],    0.0f)*w2r[0]
            + fmaxf(ac[1][rg] + BASE[16+c16], 0.0f)*w2r[1]
            + fmaxf(ac[2][rg] + BASE[32+c16], 0.0f)*w2r[2]
            + fmaxf(ac[3][rg] + BASE[48+c16], 0.0f)*w2r[3];
    v += __shfl_xor(v, 1); v += __shfl_xor(v, 2);
    v += __shfl_xor(v, 4); v += __shfl_xor(v, 8);
    const int row = mt*16 + quad*4 + rg;
    if (c16 == 0 && row < t) atomicAdd(&LOGI[row], v);
  }
}

// ll partial for generation tg_ (rows [16r,16r+16) ∩ [0,tg_)), wave-wide
__device__ __forceinline__ void ll_gen(int tg_, int r, int lane, float b2v,
    const unsigned* LOGPb, const unsigned* RBIT, const unsigned* ANCW,
    float* out_ll)
{
  const int pp = tg_ & 1;
  const int row = 16*r + (lane >> 2);
  float term = 0.0f;
  if (row < tg_) {
    const unsigned* Lp = LOGPb + pp*1024;
    const int rr = (lane & 3)*2;
    float s = __uint_as_float(ald32(Lp + rr*128 + row))
            + __uint_as_float(ald32(Lp + (rr+1)*128 + row));
    s += __shfl_xor(s, 1); s += __shfl_xor(s, 2);
    if ((lane & 3) == 0) {
      const int w = row >> 5;
      const float anc = (float)((ANCW[pp*4 + w] >> (row & 31)) & 1u);
      float q = sigm(b2v + s) * (1.0f - 0.5f*anc);
      q = fminf(fmaxf(q, 1e-6f), 1.0f - 1e-6f);
      const unsigned rb = (RBIT[pp*4 + w] >> (row & 31)) & 1u;
      term = rb ? logf(q) : log1pf(-q);
    }
  }
  #pragma unroll
  for (int off = 1; off < 64; off <<= 1) term += __shfl_xor(term, off);
  if (lane == 0) atomicAdd(out_ll, term);
}

// ---------- main: 256 blocks (batch b = blk%32, slice r = blk/32 -> same XCD) ----------
// amdgpu_waves_per_eu(4,4): exactly 4 waves/SIMD -> 128-VGPR budget.
// (R7 showed __launch_bounds__'s 2nd arg is ignored: VGPR stayed 64 -> scratch spill.)
__global__ void __launch_bounds__(NT)
__attribute__((amdgpu_waves_per_eu(4, 4)))
decoder_main(
    const int* __restrict__ tg,
    const float* __restrict__ bx, const float* __restrict__ bh,
    const float* __restrict__ b1, const float* __restrict__ W2,
    const float* __restrict__ b2,
    float* __restrict__ ws, float* __restrict__ out)
{
  const int blk = blockIdx.x;
  const int b = blk & 31, r = blk >> 5;
  const int tid = threadIdx.x;
  const int lane = tid & 63, w = tid >> 6;
  const int c16 = lane & 15, quad = lane >> 4;

  extern __shared__ char smem[];
  uint4* SW4 = (uint4*)(smem + SM_SW);
  unsigned short* SST = (unsigned short*)(smem + SM_SST);
  unsigned long long* SST64 = (unsigned long long*)(smem + SM_SST);
  unsigned short* NLDS = (unsigned short*)(smem + SM_NLDS);
  unsigned* NLDSu = (unsigned*)(smem + SM_NLDS);
  unsigned long long* NLDS64 = (unsigned long long*)(smem + SM_NLDS);
  float* GXF  = (float*)(smem + SM_GXF);
  unsigned short* HPF = (unsigned short*)(smem + SM_HPF);
  float* GX2  = (float*)(smem + SM_GX2);
  float* GHT  = (float*)(smem + SM_GHT);
  float* BASE = (float*)(smem + SM_BASE);
  float* BHS  = (float*)(smem + SM_BHS);
  float* PSN  = (float*)(smem + SM_PSN);
  float* LOGI = (float*)(smem + SM_LOGI);
  unsigned char* TGRu = (unsigned char*)(smem + SM_TGR);
  unsigned* RBIT  = (unsigned*)(smem + SM_RBIT);   // [2][4]
  unsigned* ANCW  = (unsigned*)(smem + SM_ANCW);   // [2][4]
  unsigned* AMASK = (unsigned*)(smem + SM_AMASK);

  const float* __restrict__ h0g  = ws + WS_H0  + b*Hh;
  const float* __restrict__ gh0g = ws + WS_GH0 + b*Gg;
  const float* __restrict__ zW1g = ws + WS_ZW1 + b*Ff;
  unsigned* GXPb = (unsigned*)(ws + WS_GXP) + b*2*8*Gg;       // [2][8][768]
  unsigned* LOGPb = (unsigned*)(ws + WS_LOGP) + b*2*8*Nn;     // [2][8][128]
  unsigned* bar = (unsigned*)(ws + WS_BAR) + b*32;
  unsigned long long* XS64b = (unsigned long long*)(ws + WS_XS) + b*16384; // [2][8mt][8ks][128]
  const uint4* WB4 = (const uint4*)(ws + WS_WB);
  float* out_ll = out + Bz*Nn*Nn + b;

  // ---- prologue ----
  for (int i = tid; i < 16384; i += NT) ((unsigned*)SST)[i] = 0u;   // zero mirror
  for (int i = tid; i < 4096; i += NT) NLDSu[i] = 0u;               // zero NLDS
  for (int i = tid; i < 5120; i += NT) {   // weight slices -> LDS (10 tiles)
    const int lt = i >> 9, q = i & 511;
    int gt;
    if (lt < 6) { const int gate = lt >> 1, tt = lt & 1; gt = gate*16 + 2*r + tt; }
    else        { gt = 48 + 4*r + (lt - 6); }
    SW4[lt*512 + q] = WB4[gt*512 + q];
  }
  for (int i = tid; i < Nn*4; i += NT) AMASK[i] = 0u;
  if (tid < 96) BHS[tid] = bh[(tid >> 5)*256 + 32*r + (tid & 31)];
  if (tid < 128) TGRu[128 + tid] = (unsigned char)tg[b*Nn*Nn + 1*Nn + tid]; // row 1 -> parity 1
  float w2r[4];
  #pragma unroll
  for (int ft = 0; ft < 4; ++ft) w2r[ft] = W2[64*r + ft*16 + c16];
  const float b2v = b2[0];
  // per-lane h_prov constants + matvec job constants (waves 8-15 only)
  float p_bx[3][4], p_gh[3][4], p_h0[4];
  int colj[2]; float auxj[2];
  if (w >= 8) {
    #pragma unroll
    for (int k = 0; k < 4; ++k) {
      const int c = 4*lane + k;
      p_h0[k] = h0g[c];
      #pragma unroll
      for (int g3 = 0; g3 < 3; ++g3) {
        p_bx[g3][k] = bx[g3*256 + c];
        p_gh[g3][k] = gh0g[g3*256 + c];
      }
    }
    #pragma unroll
    for (int jj = 0; jj < 2; ++jj) {
      const int j = (w - 8) + 8*jj;   // jj=0 -> 0..7, jj=1 -> 8..15
      colj[jj] = 0; auxj[jj] = 0.0f;
      if (j >= 6 && j < 12) {
        const int jx = j - 6, g = jx >> 1, tt = jx & 1;
        const int col = g*256 + 32*r + tt*16 + c16;
        colj[jj] = col; auxj[jj] = bx[col];
      } else if (j >= 12) {
        const int ft = j - 12, f = 64*r + ft*16 + c16;
        auxj[jj] = zW1g[f] + b1[f];
      }
    }
  }
  unsigned bseq = 0;
  __syncthreads();
  if (tid < Hh) {   // mirror row 0 = h0
    const int c = tid;
    SST[(c>>5)*512 + ((c>>3)&3)*128 + (c&7)] = f2bf(h0g[c]);
  }
  if (tid < 32) PSN[tid] = h0g[32*r + tid];   // col-sums after "row 0 only"
  __syncthreads();
  // gx1p(t=1) partial into GXP parity 1 + publish state tile 0 (gen 0 -> XS parity 0)
  {
    union { unsigned u[4]; v8s v; } cv;
    const float4 a0 = *(const float4*)(PSN + quad*8);
    const float4 a1 = *(const float4*)(PSN + quad*8 + 4);
    cv.u[0] = pkbf(a0.x, a0.y); cv.u[1] = pkbf(a0.z, a0.w);
    cv.u[2] = pkbf(a1.x, a1.y); cv.u[3] = pkbf(a1.z, a1.w);
    const v8s avp = cv.v;
    unsigned* GXPw = GXPb + 1*8*Gg + r*Gg;
    #pragma unroll
    for (int k2 = 0; k2 < 3; ++k2) {
      const int nt = w*3 + k2;
      f4 c = {0.0f,0.0f,0.0f,0.0f};
      c = MFMA(avp, u4v(WB4[(80 + nt)*512 + r*64 + lane]), c);
      if (quad == 0) ast32(GXPw + nt*16 + c16, __float_as_uint(c[0]));
    }
  }
  if (tid < 128) ast64(XS64b + r*128 + tid, SST64[r*128 + tid]);
  bbar(bar, bseq);   // B0

  for (int t = 1; t < Nn; ++t) {
    const int tp = t & 1;
    const float invt  = 1.0f / (float)t;
    const float invt1 = 1.0f / (float)(t + 1);
    const int Mr   = (t + 15) >> 4;     // tiles covering rows 0..t-1
    const int Mtot = (t + 16) >> 4;     // tiles covering rows 0..t
    const int mtc  = t >> 4;            // tile holding row t
    const int nG = (Mr + 1) >> 1;
    const int njobs = 2*nG;             // in {2,4,6,8}
    const unsigned long long* XSr = XS64b + (1-tp)*8192;   // gen t-1
    unsigned long long* XSw = XS64b + tp*8192;             // gen t

    // ======== S0: GXF (w0-5) | refresh (w6-13) | aux (w14) | ll(t-1) (w15) ========
    if (w < 6) {
      const unsigned long long* GXPr = (const unsigned long long*)(GXPb + tp*8*Gg);
      unsigned long long g[8];
      #pragma unroll
      for (int rr = 0; rr < 8; ++rr) g[rr] = ald64(GXPr + rr*384 + tid);
      float s0 = 0.0f, s1 = 0.0f;
      #pragma unroll
      for (int rr = 0; rr < 8; ++rr) {
        s0 += __uint_as_float((unsigned)g[rr]);
        s1 += __uint_as_float((unsigned)(g[rr] >> 32));
      }
      GXF[2*tid]   = s0;
      GXF[2*tid+1] = s1;
    } else if (w < 14) {
      const int idx = tid - 384;        // 0..511
      for (int i = idx; i < Mr*1024; i += 512) {
        if (((i >> 7) & 7) != r) SST64[i] = ald64(XSr + i);
      }
    } else if (w == 14) {
      const int v0 = TGRu[tp*128 + lane];
      const int v1 = TGRu[tp*128 + 64 + lane];
      const unsigned long long bal0 = __ballot(lane < t && v0);
      const unsigned long long bal1 = __ballot((lane + 64) < t && v1);
      unsigned m0=0,m1=0,m2=0,m3=0;
      if (lane < t && v0) {
        m0 = AMASK[lane*4+0]; m1 = AMASK[lane*4+1];
        m2 = AMASK[lane*4+2]; m3 = AMASK[lane*4+3];
      }
      if (lane + 64 < t && v1) {
        m0 |= AMASK[(lane+64)*4+0]; m1 |= AMASK[(lane+64)*4+1];
        m2 |= AMASK[(lane+64)*4+2]; m3 |= AMASK[(lane+64)*4+3];
      }
      #pragma unroll
      for (int off = 1; off < 64; off <<= 1) {
        m0 |= __shfl_xor(m0, off); m1 |= __shfl_xor(m1, off);
        m2 |= __shfl_xor(m2, off); m3 |= __shfl_xor(m3, off);
      }
      LOGI[lane] = 0.0f; LOGI[lane + 64] = 0.0f;
      if (lane < 32) PSN[lane] = 0.0f;
      if (lane < 4) {
        const unsigned rbw = (lane == 0) ? (unsigned)bal0 :
                             (lane == 1) ? (unsigned)(bal0 >> 32) :
                             (lane == 2) ? (unsigned)bal1 : (unsigned)(bal1 >> 32);
        const unsigned anw = (lane == 0) ? m0 : (lane == 1) ? m1 : (lane == 2) ? m2 : m3;
        RBIT[tp*4 + lane] = rbw;
        ANCW[tp*4 + lane] = anw;
      }
    } else {
      if (t > 1) ll_gen(t-1, r, lane, b2v, LOGPb, RBIT, ANCW, out_ll);
    }
    __syncthreads();

    // ======== S1: big GEMM MFMA (w0-7) || h_prov + 16 matvecs (w8-15) ========
    f4 acc[12];
    #pragma unroll
    for (int i = 0; i < 12; ++i) acc[i] = (f4){0.0f,0.0f,0.0f,0.0f};
    int kindA = 0, mtA = 0; bool haveA = false, d1A = false;
    if (w < 8) {
      if (w < njobs) {
        haveA = true;
        if (w < nG) { kindA = 0; mtA = 2*w; }
        else        { kindA = 1; mtA = 2*(w - nG); }
        d1A = (mtA + 1 < Mr);
        if (kindA == 0) G_mfma(SST, SW4, mtA, d1A, lane, acc);
        else            L_mfma(SST, SW4, mtA, d1A, lane, acc);
      }
    } else {
      if (w == 8 && lane < 4)
        AMASK[t*4 + lane] = RBIT[tp*4 + lane] | ANCW[tp*4 + lane];
      if (w == 9 && (t & 15) == 0) {   // zero fresh NLDS tile for row t
        for (int q = lane; q < 256; q += 64) NLDSu[mtc*256 + q] = 0u;
      }
      // h_prov: each of waves 8-15 computes ALL 256 values (redundant, identical)
      {
        float hp[4];
        #pragma unroll
        for (int k = 0; k < 4; ++k) {
          const int c = 4*lane + k;
          const float rv = sigm(GXF[c]*invt       + p_bx[0][k] + p_gh[0][k]);
          const float uv = sigm(GXF[256+c]*invt   + p_bx[1][k] + p_gh[1][k]);
          const float nv = tanh_fast(GXF[512+c]*invt + p_bx[2][k] + rv*p_gh[2][k]);
          hp[k] = (1.0f - uv)*nv + uv*p_h0[k];
        }
        uint2 pk;
        pk.x = pack2(hp[0], hp[1]); pk.y = pack2(hp[2], hp[3]);
        *(uint2*)(HPF + 4*lane) = pk;
      }
      // 16 small matvecs, 2 per wave
      {
        v8s av[8];
        #pragma unroll
        for (int ks = 0; ks < 8; ++ks) av[ks] = *(const v8s*)(HPF + ks*32 + quad*8);
        #pragma unroll
        for (int jj = 0; jj < 2; ++jj) {
          const int j = (w - 8) + 8*jj;
          f4 c = {0.0f,0.0f,0.0f,0.0f};
          if (j < 6) {
            #pragma unroll
            for (int ks = 0; ks < 8; ++ks) c = MFMA(av[ks], u4v(SW4[(j*8 + ks)*64 + lane]), c);
            if (quad == 0) GHT[(j>>1)*32 + (j&1)*16 + c16] = c[0];
          } else if (j < 12) {
            const int jx = j - 6, g = jx >> 1, tt = jx & 1;
            const uint4* Bp = WB4 + (80 + g*16 + 2*r + tt)*512 + lane;
            #pragma unroll
            for (int ks = 0; ks < 8; ++ks) c = MFMA(av[ks], u4v(Bp[ks*64]), c);
            if (quad == 0) GX2[g*32 + tt*16 + c16] = (c[0] + GXF[colj[jj]])*invt1 + auxj[jj];
          } else {
            const int ft = j - 12;
            const uint4* Bp = WB4 + (128 + 4*r + ft)*512 + lane;
            #pragma unroll
            for (int ks = 0; ks < 8; ++ks) c = MFMA(av[ks], u4v(Bp[ks*64]), c);
            if (quad == 0) BASE[ft*16 + c16] = c[0] + auxj[jj];
          }
        }
      }
    }
    __syncthreads();

    // ======== S2: epilogues (w0-7); row-t GRU cell (w8) ========
    if (w < 8) {
      if (haveA) {
        if (kindA == 0) {
          G_epi(acc,     mtA,   t, r, quad, c16, lane, GX2, BHS, SST, NLDS, PSN);
          if (d1A) G_epi(acc+6, mtA+1, t, r, quad, c16, lane, GX2, BHS, SST, NLDS, PSN);
        } else {
          L_epi(acc,     mtA,   t, quad, c16, BASE, w2r, LOGI);
          if (d1A) L_epi(acc+4, mtA+1, t, quad, c16, BASE, w2r, LOGI);
        }
      }
    } else if (w == 8 && lane < 32) {
      const int hcl = lane;
      const float rv = sigm(GX2[hcl]    + GHT[hcl]    + BHS[hcl]);
      const float uv = sigm(GX2[32+hcl] + GHT[32+hcl] + BHS[32+hcl]);
      const float nv = tanh_fast(GX2[64+hcl] + rv*(GHT[64+hcl] + BHS[64+hcl]));
      const float old = bf2f(HPF[32*r + hcl]);
      const float ns = (1.0f - uv)*nv + uv*old;
      const int spi = ((hcl>>3)*16 + (t & 15))*8 + (hcl & 7);
      NLDS[mtc*512 + spi] = f2bf(ns);
      atomicAdd(&PSN[hcl], ns);
    }
    __syncthreads();   // NLDS/PSN/LOGI complete

    // ======== S3: gx1p(t+1) + publish states/logits + prefetch + bbar ========
    {
      union { unsigned u[4]; v8s v; } cv;
      const float4 a0 = *(const float4*)(PSN + quad*8);
      const float4 a1 = *(const float4*)(PSN + quad*8 + 4);
      cv.u[0] = pkbf(a0.x, a0.y); cv.u[1] = pkbf(a0.z, a0.w);
      cv.u[2] = pkbf(a1.x, a1.y); cv.u[3] = pkbf(a1.z, a1.w);
      const v8s avp = cv.v;
      unsigned* GXPw = GXPb + ((t+1)&1)*8*Gg + r*Gg;
      #pragma unroll
      for (int k2 = 0; k2 < 3; ++k2) {
        const int nt = w*3 + k2;
        f4 c = {0.0f,0.0f,0.0f,0.0f};
        c = MFMA(avp, u4v(WB4[(80 + nt)*512 + r*64 + lane]), c);
        if (quad == 0) ast32(GXPw + nt*16 + c16, __float_as_uint(c[0]));
      }
    }
    for (int i = tid; i < Mtot*128; i += NT) {
      const int mt = i >> 7, q = i & 127;
      const unsigned long long v = NLDS64[i];
      ast64(XSw + (mt*8 + r)*128 + q, v);
      SST64[(mt*8 + r)*128 + q] = v;            // own chunk updated locally
    }
    if (tid < 64)
      ast64((unsigned long long*)LOGPb + tp*512 + r*64 + tid,
            ((const unsigned long long*)LOGI)[tid]);
    if (w == 14 && t + 1 < Nn) {   // teacher row t+1 -> LDS
      const int base = b*Nn*Nn + (t+1)*Nn;
      TGRu[((t+1)&1)*128 + lane]      = (unsigned char)tg[base + lane];
      TGRu[((t+1)&1)*128 + lane + 64] = (unsigned char)tg[base + lane + 64];
    }
    bbar(bar, bseq);   // gen-t states/logits/gx1p visible
  }

  // ---- epilogue: ll for gen 127 (distributed; final bbar ensured visibility) ----
  if (w == 15) ll_gen(Nn - 1, r, lane, b2v, LOGPb, RBIT, ANCW, out_ll);
}

extern "C" void kernel_launch(void* const* d_in, const int* in_sizes, int n_in,
                              void* d_out, int out_size, void* d_ws, size_t ws_size,
                              hipStream_t stream)
{
  const float* z  = (const float*)d_in[0];
  const int*   tg = (const int*)  d_in[1];
  const float* Wi = (const float*)d_in[2];
  const float* bi = (const float*)d_in[3];
  const float* Wx = (const float*)d_in[4];
  const float* Wh = (const float*)d_in[5];
  const float* bx = (const float*)d_in[6];
  const float* bh = (const float*)d_in[7];
  const float* W1 = (const float*)d_in[8];
  const float* b1 = (const float*)d_in[9];
  const float* W2 = (const float*)d_in[10];
  const float* b2 = (const float*)d_in[11];
  float* out = (float*)d_out;
  float* ws  = (float*)d_ws;

  hipFuncSetAttribute((const void*)decoder_main,
                      hipFuncAttributeMaxDynamicSharedMemorySize, SMEM_SZ);

  hipLaunchKernelGGL(prep_init, dim3(512), dim3(256), 0, stream, tg, Wx, Wh, W1, ws, out);
  hipLaunchKernelGGL(prep_batch, dim3(Bz), dim3(256), 0, stream, z, Wi, bi, Wh, bh, W1, ws);

  void* args[] = { (void*)&tg, (void*)&bx, (void*)&bh, (void*)&b1,
                   (void*)&W2, (void*)&b2, (void*)&ws, (void*)&out };
  hipLaunchCooperativeKernel((void*)decoder_main, dim3(256), dim3(NT),
                             args, SMEM_SZ, stream);
}

// Round 9
// 1963.373 us; speedup vs baseline: 1.6654x; 1.6654x over previous
//
#include <hip/hip_runtime.h>
#include <hip/hip_bf16.h>
#include <math.h>

// Problem constants
#define Bz 32
#define Nn 128
#define Hh 256
#define Dd 256
#define Ff 512
#define Gg 768
#define NT 512          // 8 waves per block; 256 blocks = 32 batches x 8 col-slices

typedef short v8s __attribute__((ext_vector_type(8)));   // 8 bf16
typedef float f4  __attribute__((ext_vector_type(4)));   // MFMA C/D
#define MFMA(a,b,c) __builtin_amdgcn_mfma_f32_16x16x32_bf16(a,b,c,0,0,0)

// Workspace layout (float elements)
#define WS_H0    0                          // [B][256]
#define WS_GH0   (WS_H0 + Bz*Hh)            // [B][768]  h0@Wh + bh
#define WS_ZW1   (WS_GH0 + Bz*Gg)           // [B][512]  z@W1c
#define WS_GXP   (WS_ZW1 + Bz*Ff)           // [B][2][8][768] gx1 partials (parity)
#define WS_LOGP  (WS_GXP + Bz*2*8*Gg)       // [B][2][8][128] logit partials (parity)
#define WS_BAR   (WS_LOGP + Bz*2*8*Nn)      // [B][32] uint barrier counters
#define WS_XS    (WS_BAR + Bz*32)           // [B][2][8mt][8ks][128 u64] state exchange (parity)
#define WS_WB    (WS_XS + Bz*32768)         // [160][8][64][4] uint B-frag packed weights

// LDS layout (bytes) — total <= 163840
#define SM_SW    0         // [10 lt][8 ks][64 lane] uint4 : 6 Wh + 4 W1b tiles (81920)
#define SM_SST   81920     // ushort[8mt][8ks][512] bf16 state mirror (65536)
#define SM_NLDS  147456    // ushort[8mt][512] new-state own-slice staging (8192)
#define SM_GXF   155648    // float[768] full gx1 (unscaled pooled-sum @ Wx)
#define SM_HPF   158720    // ushort[256] h_prov bf16
#define SM_GX2   159232    // float[96]
#define SM_GHT   159616    // float[96]  hp @ Wh (own gate cols)
#define SM_BASE  160000    // float[64]
#define SM_BHS   160256    // float[96]
#define SM_PSN   160640    // float[32]
#define SM_LOGI  160768    // float[128]
#define SM_RBIT  161280    // uint[2 par][4]
#define SM_ANCW  161312    // uint[2 par][2 wave][4]
#define SM_AMASK 161376    // uint[128][4]
#define SMEM_SZ  163424

__device__ __forceinline__ unsigned short f2bf(float x) {
  unsigned u = __float_as_uint(x);
  u = u + 0x7fffu + ((u >> 16) & 1u);   // RNE
  return (unsigned short)(u >> 16);
}
__device__ __forceinline__ unsigned pack2(float e, float o) {
  return (unsigned)f2bf(e) | ((unsigned)f2bf(o) << 16);
}
__device__ __forceinline__ unsigned pkbf(float x, float y) {
  __hip_bfloat162 h = __float22bfloat162_rn(make_float2(x, y));
  union { __hip_bfloat162 h; unsigned u; } c; c.h = h; return c.u;
}
__device__ __forceinline__ float bf2f(unsigned short s) {
  return __uint_as_float(((unsigned)s) << 16);
}
__device__ __forceinline__ float sigm(float x) { return 1.0f / (1.0f + __expf(-x)); }
__device__ __forceinline__ float tanh_fast(float x) { return 2.0f / (1.0f + __expf(-2.0f*x)) - 1.0f; }
__device__ __forceinline__ v8s u4v(uint4 q) { union { uint4 q; v8s v; } c; c.q = q; return c.v; }

// Relaxed AGENT atomics
__device__ __forceinline__ void ast32(unsigned* p, unsigned v) {
  __hip_atomic_store(p, v, __ATOMIC_RELAXED, __HIP_MEMORY_SCOPE_AGENT);
}
__device__ __forceinline__ unsigned ald32(const unsigned* p) {
  return __hip_atomic_load(p, __ATOMIC_RELAXED, __HIP_MEMORY_SCOPE_AGENT);
}
__device__ __forceinline__ void ast64(unsigned long long* p, unsigned long long v) {
  __hip_atomic_store(p, v, __ATOMIC_RELAXED, __HIP_MEMORY_SCOPE_AGENT);
}
__device__ __forceinline__ unsigned long long ald64(const unsigned long long* p) {
  return __hip_atomic_load(p, __ATOMIC_RELAXED, __HIP_MEMORY_SCOPE_AGENT);
}

// per-batch barrier among 8 blocks (proven best sync primitive: 1-thread poll + s_sleep)
__device__ __forceinline__ void bbar(unsigned* cnt, unsigned& seq)
{
  __builtin_amdgcn_s_waitcnt(0x0F70);   // vmcnt(0)
  __syncthreads();
  seq += 8;
  if (threadIdx.x == 0) {
    __hip_atomic_fetch_add(cnt, 1u, __ATOMIC_RELAXED, __HIP_MEMORY_SCOPE_AGENT);
    while (__hip_atomic_load(cnt, __ATOMIC_RELAXED, __HIP_MEMORY_SCOPE_AGENT) < seq)
      __builtin_amdgcn_s_sleep(1);
  }
  __syncthreads();
}

// ---------- prep 1 ----------
__global__ void __launch_bounds__(256) prep_init(
    const int* __restrict__ tg, const float* __restrict__ Wx,
    const float* __restrict__ Wh, const float* __restrict__ W1,
    float* __restrict__ ws, float* __restrict__ out)
{
  const int stride = gridDim.x * blockDim.x;
  const int t0 = blockIdx.x * blockDim.x + threadIdx.x;

  for (int i = t0; i < Bz*Nn*Nn; i += stride) {         // L = tril(targets, -1)
    int col = i & (Nn-1), row = (i >> 7) & (Nn-1);
    out[i] = (col < row) ? (float)tg[i] : 0.0f;
  }
  for (int i = t0; i < Bz; i += stride) out[Bz*Nn*Nn + i] = 0.0f;

  unsigned* BARu = (unsigned*)(ws + WS_BAR);
  for (int i = t0; i < Bz*32; i += stride) BARu[i] = 0u;

  // B-frag packing: regions [0,48) Wh | [48,80) W1b | [80,128) Wx | [128,160) W1a
  unsigned* Wb = (unsigned*)(ws + WS_WB);
  for (int i = t0; i < 160*2048; i += stride) {
    int jw = i & 3, l = (i >> 2) & 63, ks = (i >> 8) & 7, nt = i >> 11;
    int k = ks*32 + (l >> 4)*8 + 2*jw;
    int n16 = l & 15;
    float lo, hi;
    if (nt < 48)       { int c = nt*16 + n16;        lo = Wh[k*Gg + c];      hi = Wh[(k+1)*Gg + c]; }
    else if (nt < 80)  { int f = (nt-48)*16 + n16;   lo = W1[(Hh+k)*Ff + f]; hi = W1[(Hh+k+1)*Ff + f]; }
    else if (nt < 128) { int c = (nt-80)*16 + n16;   lo = Wx[k*Gg + c];      hi = Wx[(k+1)*Gg + c]; }
    else               { int f = (nt-128)*16 + n16;  lo = W1[k*Ff + f];      hi = W1[(k+1)*Ff + f]; }
    Wb[i] = pack2(lo, hi);
  }
}

// ---------- prep 2 ----------
__global__ void __launch_bounds__(256) prep_batch(
    const float* __restrict__ z, const float* __restrict__ Wi,
    const float* __restrict__ bi, const float* __restrict__ Wh,
    const float* __restrict__ bh, const float* __restrict__ W1,
    float* __restrict__ ws)
{
  const int b = blockIdx.x, tid = threadIdx.x;
  __shared__ float zs[Dd], h0s[Hh];
  zs[tid] = z[b*Dd + tid];
  __syncthreads();
  float acc = bi[tid];
  for (int d = 0; d < Dd; ++d) acc = fmaf(zs[d], Wi[d*Hh + tid], acc);
  const float h0 = tanhf(acc);
  h0s[tid] = h0;
  ws[WS_H0 + b*Hh + tid] = h0;
  __syncthreads();
  for (int g = tid; g < Gg; g += 256) {
    float a = bh[g];
    for (int h = 0; h < Hh; ++h) a = fmaf(h0s[h], Wh[h*Gg + g], a);
    ws[WS_GH0 + b*Gg + g] = a;
  }
  for (int f = tid; f < Ff; f += 256) {
    float a = 0.0f;
    for (int d = 0; d < Dd; ++d) a = fmaf(zs[d], W1[(2*Hh + d)*Ff + f], a);
    ws[WS_ZW1 + b*Ff + f] = a;
  }
}

// GEMM jobs (MFMA part and epilogue split across a __syncthreads)
__device__ __forceinline__ void G_mfma(const unsigned short* SST, const uint4* SW4,
    int mt0, bool do1, int lane, f4* acc)
{
  #pragma unroll
  for (int ks = 0; ks < 8; ++ks) {
    const v8s a0 = *(const v8s*)(SST + (mt0*8 + ks)*512 + lane*8);
    const v8s w0 = u4v(SW4[(0*8 + ks)*64 + lane]);
    const v8s w1 = u4v(SW4[(1*8 + ks)*64 + lane]);
    const v8s w2 = u4v(SW4[(2*8 + ks)*64 + lane]);
    const v8s w3 = u4v(SW4[(3*8 + ks)*64 + lane]);
    const v8s w4 = u4v(SW4[(4*8 + ks)*64 + lane]);
    const v8s w5 = u4v(SW4[(5*8 + ks)*64 + lane]);
    acc[0] = MFMA(a0,w0,acc[0]); acc[1] = MFMA(a0,w1,acc[1]);
    acc[2] = MFMA(a0,w2,acc[2]); acc[3] = MFMA(a0,w3,acc[3]);
    acc[4] = MFMA(a0,w4,acc[4]); acc[5] = MFMA(a0,w5,acc[5]);
    if (do1) {
      const v8s a1 = *(const v8s*)(SST + ((mt0+1)*8 + ks)*512 + lane*8);
      acc[6]  = MFMA(a1,w0,acc[6]);  acc[7]  = MFMA(a1,w1,acc[7]);
      acc[8]  = MFMA(a1,w2,acc[8]);  acc[9]  = MFMA(a1,w3,acc[9]);
      acc[10] = MFMA(a1,w4,acc[10]); acc[11] = MFMA(a1,w5,acc[11]);
    }
  }
}

__device__ __forceinline__ void G_epi(const f4* ac, int mt, int t, int r,
    int quad, int c16, int lane, const float* GX2, const float* BHS,
    const unsigned short* SST, unsigned short* NLDS, float* PSN)
{
  #pragma unroll
  for (int ct = 0; ct < 2; ++ct) {
    const int hcl = ct*16 + c16;
    const f4 cr = ac[0 + ct], cu = ac[2 + ct], cn = ac[4 + ct];
    const float gxr = GX2[hcl], gxu = GX2[32+hcl], gxn = GX2[64+hcl];
    const float bhr = BHS[hcl], bhu = BHS[32+hcl], bhn = BHS[64+hcl];
    float colsum = 0.0f;
    #pragma unroll
    for (int rg = 0; rg < 4; ++rg) {
      const int row = mt*16 + quad*4 + rg;
      if (row < t) {
        const int spi = ((hcl>>3)*16 + quad*4 + rg)*8 + (hcl & 7);
        const float old = bf2f(SST[(mt*8 + r)*512 + spi]);
        const float rv = sigm(gxr + cr[rg] + bhr);
        const float uv = sigm(gxu + cu[rg] + bhu);
        const float nv = tanh_fast(gxn + rv*(cn[rg] + bhn));
        const float ns = (1.0f-uv)*nv + uv*old;
        NLDS[mt*512 + spi] = f2bf(ns);
        colsum += ns;
      }
    }
    colsum += __shfl_down(colsum, 16);
    colsum += __shfl_down(colsum, 32);
    if (lane < 16) atomicAdd(&PSN[ct*16 + lane], colsum);
  }
}

__device__ __forceinline__ void L_mfma(const unsigned short* SST, const uint4* SW4,
    int mt0, bool do1, int lane, f4* acc)
{
  #pragma unroll
  for (int ks = 0; ks < 8; ++ks) {
    const v8s a0 = *(const v8s*)(SST + (mt0*8 + ks)*512 + lane*8);
    const v8s c0 = u4v(SW4[(6*8 + ks)*64 + lane]);
    const v8s c1 = u4v(SW4[(7*8 + ks)*64 + lane]);
    const v8s c2 = u4v(SW4[(8*8 + ks)*64 + lane]);
    const v8s c3 = u4v(SW4[(9*8 + ks)*64 + lane]);
    acc[0] = MFMA(a0,c0,acc[0]); acc[1] = MFMA(a0,c1,acc[1]);
    acc[2] = MFMA(a0,c2,acc[2]); acc[3] = MFMA(a0,c3,acc[3]);
    if (do1) {
      const v8s a1 = *(const v8s*)(SST + ((mt0+1)*8 + ks)*512 + lane*8);
      acc[4] = MFMA(a1,c0,acc[4]); acc[5] = MFMA(a1,c1,acc[5]);
      acc[6] = MFMA(a1,c2,acc[6]); acc[7] = MFMA(a1,c3,acc[7]);
    }
  }
}

__device__ __forceinline__ void L_epi(const f4* ac, int mt, int t,
    int quad, int c16, const float* BASE, const float* w2r, float* LOGI)
{
  #pragma unroll
  for (int rg = 0; rg < 4; ++rg) {
    float v = fmaxf(ac[0][rg] + BASE[c16],    0.0f)*w2r[0]
            + fmaxf(ac[1][rg] + BASE[16+c16], 0.0f)*w2r[1]
            + fmaxf(ac[2][rg] + BASE[32+c16], 0.0f)*w2r[2]
            + fmaxf(ac[3][rg] + BASE[48+c16], 0.0f)*w2r[3];
    v += __shfl_xor(v, 1); v += __shfl_xor(v, 2);
    v += __shfl_xor(v, 4); v += __shfl_xor(v, 8);
    const int row = mt*16 + quad*4 + rg;
    if (c16 == 0 && row < t) atomicAdd(&LOGI[row], v);
  }
}

// ---------- main: 256 blocks (batch b = blk%32, slice r = blk/32 -> same XCD) ----------
__global__ void __launch_bounds__(NT) decoder_main(
    const int* __restrict__ tg,
    const float* __restrict__ bx, const float* __restrict__ bh,
    const float* __restrict__ b1, const float* __restrict__ W2,
    const float* __restrict__ b2,
    float* __restrict__ ws, float* __restrict__ out)
{
  const int blk = blockIdx.x;
  const int b = blk & 31, r = blk >> 5;
  const int tid = threadIdx.x;
  const int lane = tid & 63, wv = tid >> 6;
  const int c16 = lane & 15, quad = lane >> 4;

  extern __shared__ char smem[];
  uint4* SW4 = (uint4*)(smem + SM_SW);
  unsigned short* SST = (unsigned short*)(smem + SM_SST);
  unsigned long long* SST64 = (unsigned long long*)(smem + SM_SST);
  unsigned short* NLDS = (unsigned short*)(smem + SM_NLDS);
  unsigned* NLDSu = (unsigned*)(smem + SM_NLDS);
  unsigned long long* NLDS64 = (unsigned long long*)(smem + SM_NLDS);
  float* GXF  = (float*)(smem + SM_GXF);
  unsigned short* HPF = (unsigned short*)(smem + SM_HPF);
  float* GX2  = (float*)(smem + SM_GX2);
  float* GHT  = (float*)(smem + SM_GHT);
  float* BASE = (float*)(smem + SM_BASE);
  float* BHS  = (float*)(smem + SM_BHS);
  float* PSN  = (float*)(smem + SM_PSN);
  float* LOGI = (float*)(smem + SM_LOGI);
  unsigned* RBIT  = (unsigned*)(smem + SM_RBIT);   // [2][4]
  unsigned* ANCW  = (unsigned*)(smem + SM_ANCW);   // [2][2][4]
  unsigned* AMASK = (unsigned*)(smem + SM_AMASK);

  const float* __restrict__ h0g  = ws + WS_H0  + b*Hh;
  const float* __restrict__ gh0g = ws + WS_GH0 + b*Gg;
  const float* __restrict__ zW1g = ws + WS_ZW1 + b*Ff;
  unsigned* GXPb = (unsigned*)(ws + WS_GXP) + b*2*8*Gg;       // [2][8][768]
  unsigned* LOGPb = (unsigned*)(ws + WS_LOGP) + b*2*8*Nn;     // [2][8][128]
  unsigned* bar = (unsigned*)(ws + WS_BAR) + b*32;
  unsigned long long* XS64b = (unsigned long long*)(ws + WS_XS) + b*16384; // [2][8mt][8ks][128]
  const uint4* WB4 = (const uint4*)(ws + WS_WB);

  // ---- prologue ----
  for (int i = tid; i < 16384; i += NT) ((unsigned*)SST)[i] = 0u;   // zero mirror
  for (int i = tid; i < 4096; i += NT) NLDSu[i] = 0u;               // zero NLDS
  for (int i = tid; i < 5120; i += NT) {   // weight slices -> LDS (10 tiles)
    const int lt = i >> 9, q = i & 511;
    int gt;
    if (lt < 6) { const int gate = lt >> 1, tt = lt & 1; gt = gate*16 + 2*r + tt; }
    else        { gt = 48 + 4*r + (lt - 6); }
    SW4[lt*512 + q] = WB4[gt*512 + q];
  }
  for (int i = tid; i < Nn*4; i += NT) AMASK[i] = 0u;
  if (tid < 96) BHS[tid] = bh[(tid >> 5)*256 + 32*r + (tid & 31)];
  float w2r[4];
  #pragma unroll
  for (int ft = 0; ft < 4; ++ft) w2r[ft] = W2[64*r + ft*16 + c16];
  const float b2v = b2[0];
  // h_prov per-lane constants (waves 6-7 only)
  float p_bx[3][4], p_gh[3][4], p_h0[4];
  if (wv >= 6) {
    #pragma unroll
    for (int k = 0; k < 4; ++k) {
      const int c = 4*lane + k;
      p_h0[k] = h0g[c];
      #pragma unroll
      for (int g3 = 0; g3 < 3; ++g3) {
        p_bx[g3][k] = bx[g3*256 + c];
        p_gh[g3][k] = gh0g[g3*256 + c];
      }
    }
  }
  unsigned bseq = 0;
  __syncthreads();
  if (tid < Hh) {   // mirror row 0 = h0
    const int c = tid;
    SST[(c>>5)*512 + ((c>>3)&3)*128 + (c&7)] = f2bf(h0g[c]);
  }
  if (tid < 32) PSN[tid] = h0g[32*r + tid];   // col-sums after "row 0 only"
  __syncthreads();
  // gx1p(t=1) partial into GXP parity 1 + publish state tile 0 (gen 0 -> XS parity 0)
  {
    union { unsigned u[4]; v8s v; } cv;
    const float4 a0 = *(const float4*)(PSN + quad*8);
    const float4 a1 = *(const float4*)(PSN + quad*8 + 4);
    cv.u[0] = pkbf(a0.x, a0.y); cv.u[1] = pkbf(a0.z, a0.w);
    cv.u[2] = pkbf(a1.x, a1.y); cv.u[3] = pkbf(a1.z, a1.w);
    const v8s avp = cv.v;
    unsigned* GXPw = GXPb + 1*8*Gg + r*Gg;
    #pragma unroll
    for (int k2 = 0; k2 < 6; ++k2) {
      const int nt = wv*6 + k2;
      f4 c = {0.0f,0.0f,0.0f,0.0f};
      c = MFMA(avp, u4v(WB4[(80 + nt)*512 + r*64 + lane]), c);
      if (quad == 0) ast32(GXPw + nt*16 + c16, __float_as_uint(c[0]));
    }
  }
  if (tid < 128) ast64(XS64b + r*128 + tid, SST64[r*128 + tid]);   // parity 0
  bbar(bar, bseq);   // B0

  for (int t = 1; t < Nn; ++t) {
    const int tpar = t & 1;
    const float invt  = 1.0f / (float)t;
    const float invt1 = 1.0f / (float)(t + 1);
    const int Mr   = (t + 15) >> 4;     // tiles covering rows 0..t-1
    const int Mtot = (t + 16) >> 4;     // tiles covering rows 0..t
    const int mtc  = t >> 4;            // tile holding row t
    const int nG = (Mr + 1) >> 1, nL = (Mr + 1) >> 1;
    const int njobs = nG + nL;
    const unsigned long long* XSr = XS64b + (1-tpar)*8192;   // gen t-1
    unsigned long long* XSw = XS64b + tpar*8192;             // gen t

    // ================= S0: refresh + GXF sum + aux + duty ll(t-1) =================
    for (int i = tid; i < Mr*1024; i += NT) {
      if (((i >> 7) & 7) != r) SST64[i] = ald64(XSr + i);
    }
    if (tid < 384) {
      const unsigned long long* GXPr =
          (const unsigned long long*)(GXPb + tpar*8*Gg);
      float s0 = 0.0f, s1 = 0.0f;
      #pragma unroll
      for (int rr = 0; rr < 8; ++rr) {
        const unsigned long long v = ald64(GXPr + rr*384 + tid);
        s0 += __uint_as_float((unsigned)v);
        s1 += __uint_as_float((unsigned)(v >> 32));
      }
      GXF[2*tid]   = s0;
      GXF[2*tid+1] = s1;
    } else {
      const int j = tid - 384;
      const int val = (j < t) ? tg[b*Nn*Nn + t*Nn + j] : 0;
      const unsigned long long bal = __ballot(val != 0);
      if (lane == 0) {
        RBIT[tpar*4 + (wv-6)*2]     = (unsigned)bal;
        RBIT[tpar*4 + (wv-6)*2 + 1] = (unsigned)(bal >> 32);
      }
      LOGI[j] = 0.0f;
      if (j < 32) PSN[j] = 0.0f;
      // ancestor OR via in-wave shfl reduction
      unsigned m0=0,m1=0,m2=0,m3=0;
      if (j < t && val != 0) {
        m0 = AMASK[j*4+0]; m1 = AMASK[j*4+1];
        m2 = AMASK[j*4+2]; m3 = AMASK[j*4+3];
      }
      #pragma unroll
      for (int off = 1; off < 64; off <<= 1) {
        m0 |= __shfl_xor(m0, off); m1 |= __shfl_xor(m1, off);
        m2 |= __shfl_xor(m2, off); m3 |= __shfl_xor(m3, off);
      }
      if (lane == 0) {
        unsigned* aw = ANCW + tpar*8 + (wv-6)*4;
        aw[0] = m0; aw[1] = m1; aw[2] = m2; aw[3] = m3;
      }
    }
    if (t > 1 && r == ((t - 1) & 7)) {      // ll for previous step
      const int pp = (t - 1) & 1;
      float term = 0.0f;
      if (tid < (t - 1)) {
        float lsum = b2v;
        const unsigned* Lp = LOGPb + pp*1024;
        #pragma unroll
        for (int rr = 0; rr < 8; ++rr)
          lsum += __uint_as_float(ald32(Lp + rr*Nn + tid));
        const int w = tid >> 5;
        const unsigned av_ = ANCW[pp*8 + w] | ANCW[pp*8 + 4 + w];
        const float anc = (float)((av_ >> (tid & 31)) & 1u);
        float q = sigm(lsum) * (1.0f - 0.5f*anc);
        q = fminf(fmaxf(q, 1e-6f), 1.0f - 1e-6f);
        const unsigned rb = (RBIT[pp*4 + w] >> (tid & 31)) & 1u;
        term = rb ? logf(q) : log1pf(-q);
      }
      if (wv < 2) {
        #pragma unroll
        for (int off = 32; off; off >>= 1) term += __shfl_down(term, off);
        if (lane == 0) atomicAdd(&out[Bz*Nn*Nn + b], term);
      }
    }
    __syncthreads();

    // ================= S1: big GEMM || h_prov + small matvecs =================
    f4 acc[12];
    #pragma unroll
    for (int i = 0; i < 12; ++i) acc[i] = (f4){0.0f,0.0f,0.0f,0.0f};
    bool haveA = false, d1A = false; int kindA = 0, mtA = 0;
    if (wv < 6) {
      if (wv < njobs && wv < 6) {
        haveA = true;
        if (wv < nG) { kindA = 0; mtA = 2*wv;       d1A = (mtA + 1 < Mr); }
        else         { kindA = 1; mtA = 2*(wv-nG);  d1A = (mtA + 1 < Mr); }
        if (kindA == 0) G_mfma(SST, SW4, mtA, d1A, lane, acc);
        else            L_mfma(SST, SW4, mtA, d1A, lane, acc);
      }
    } else {
      if (wv == 6 && lane < 4)
        AMASK[t*4 + lane] = RBIT[tpar*4 + lane] | ANCW[tpar*8 + lane] | ANCW[tpar*8 + 4 + lane];
      if ((t & 15) == 0) {   // zero fresh NLDS tile for row t
        for (int q = tid - 384; q < 256; q += 128) NLDSu[mtc*256 + q] = 0u;
      }
      // h_prov: each wave computes ALL 256 values (redundant -> no cross-wave sync)
      float hp[4];
      #pragma unroll
      for (int k = 0; k < 4; ++k) {
        const int c = 4*lane + k;
        const float rv = sigm(GXF[c]*invt       + p_bx[0][k] + p_gh[0][k]);
        const float uv = sigm(GXF[256+c]*invt   + p_bx[1][k] + p_gh[1][k]);
        const float nv = tanh_fast(GXF[512+c]*invt + p_bx[2][k] + rv*p_gh[2][k]);
        hp[k] = (1.0f - uv)*nv + uv*p_h0[k];
      }
      uint2 pk;
      pk.x = pack2(hp[0], hp[1]); pk.y = pack2(hp[2], hp[3]);
      *(uint2*)((unsigned short*)HPF + 4*lane) = pk;
      // small matvecs: hp@Wh (LDS), hp@Wx, hp@W1a (global)
      v8s av[8];
      #pragma unroll
      for (int ks = 0; ks < 8; ++ks) av[ks] = *(const v8s*)(HPF + ks*32 + quad*8);
      for (int j = wv - 6; j < 16; j += 2) {
        f4 c = {0.0f,0.0f,0.0f,0.0f};
        if (j < 6) {
          #pragma unroll
          for (int ks = 0; ks < 8; ++ks) c = MFMA(av[ks], u4v(SW4[(j*8 + ks)*64 + lane]), c);
          if (quad == 0) GHT[(j>>1)*32 + (j&1)*16 + c16] = c[0];
        } else if (j < 12) {
          const int jx = j - 6, g = jx >> 1, tt = jx & 1;
          const uint4* Bp = WB4 + (80 + g*16 + 2*r + tt)*512 + lane;
          #pragma unroll
          for (int ks = 0; ks < 8; ++ks) c = MFMA(av[ks], u4v(Bp[ks*64]), c);
          if (quad == 0) {
            const int col = g*256 + 32*r + tt*16 + c16;
            GX2[g*32 + tt*16 + c16] = (c[0] + GXF[col])*invt1 + bx[col];
          }
        } else {
          const int ft = j - 12;
          const uint4* Bp = WB4 + (128 + 4*r + ft)*512 + lane;
          #pragma unroll
          for (int ks = 0; ks < 8; ++ks) c = MFMA(av[ks], u4v(Bp[ks*64]), c);
          if (quad == 0) {
            const int f = 64*r + ft*16 + c16;
            BASE[ft*16 + c16] = c[0] + zW1g[f] + b1[f];
          }
        }
      }
    }
    __syncthreads();

    // ================= S2: epilogues + leftover jobs + row-t cell =================
    if (wv < 6) {
      if (haveA) {
        if (kindA == 0) {
          G_epi(acc,     mtA,   t, r, quad, c16, lane, GX2, BHS, SST, NLDS, PSN);
          if (d1A) G_epi(acc+6, mtA+1, t, r, quad, c16, lane, GX2, BHS, SST, NLDS, PSN);
        } else {
          L_epi(acc,     mtA,   t, quad, c16, BASE, w2r, LOGI);
          if (d1A) L_epi(acc+4, mtA+1, t, quad, c16, BASE, w2r, LOGI);
        }
      }
      if (wv < 2) {
        const int jB = 6 + wv;
        if (jB < njobs) {          // always an L-job (nG <= 4)
          const int mtB = 2*(jB - nG);
          const bool d1B = (mtB + 1 < Mr);
          f4 acc2[8];
          #pragma unroll
          for (int i = 0; i < 8; ++i) acc2[i] = (f4){0.0f,0.0f,0.0f,0.0f};
          L_mfma(SST, SW4, mtB, d1B, lane, acc2);
          L_epi(acc2,     mtB,   t, quad, c16, BASE, w2r, LOGI);
          if (d1B) L_epi(acc2+4, mtB+1, t, quad, c16, BASE, w2r, LOGI);
        }
      }
    } else if (wv == 6 && lane < 32) {
      // row-t GRU cell for own 32 cols
      const int hcl = lane;
      const float rv = sigm(GX2[hcl]    + GHT[hcl]    + BHS[hcl]);
      const float uv = sigm(GX2[32+hcl] + GHT[32+hcl] + BHS[32+hcl]);
      const float nv = tanh_fast(GX2[64+hcl] + rv*(GHT[64+hcl] + BHS[64+hcl]));
      const float old = bf2f(HPF[32*r + hcl]);
      const float ns = (1.0f - uv)*nv + uv*old;
      const int spi = ((hcl>>3)*16 + (t & 15))*8 + (hcl & 7);
      NLDS[mtc*512 + spi] = f2bf(ns);
      atomicAdd(&PSN[hcl], ns);
    }
    __syncthreads();

    // ================= S3: gx1p(t+1) + copy-out (parity) =================
    {
      union { unsigned u[4]; v8s v; } cv;
      const float4 a0 = *(const float4*)(PSN + quad*8);
      const float4 a1 = *(const float4*)(PSN + quad*8 + 4);
      cv.u[0] = pkbf(a0.x, a0.y); cv.u[1] = pkbf(a0.z, a0.w);
      cv.u[2] = pkbf(a1.x, a1.y); cv.u[3] = pkbf(a1.z, a1.w);
      const v8s avp = cv.v;
      unsigned* GXPw = GXPb + ((t+1)&1)*8*Gg + r*Gg;
      #pragma unroll
      for (int k2 = 0; k2 < 6; ++k2) {
        const int nt = wv*6 + k2;
        f4 c = {0.0f,0.0f,0.0f,0.0f};
        c = MFMA(avp, u4v(WB4[(80 + nt)*512 + r*64 + lane]), c);
        if (quad == 0) ast32(GXPw + nt*16 + c16, __float_as_uint(c[0]));
      }
    }
    for (int i = tid; i < Mtot*128; i += NT) {
      const int mt = i >> 7, q = i & 127;
      const unsigned long long v = NLDS64[i];
      ast64(XSw + (mt*8 + r)*128 + q, v);
      SST64[(mt*8 + r)*128 + q] = v;            // own chunk updated locally
    }
    if (tid < 64)
      ast64((unsigned long long*)LOGPb + tpar*512 + r*64 + tid,
            ((const unsigned long long*)LOGI)[tid]);
    bbar(bar, bseq);   // gen-t states/logits/gx1p visible
  }

  // ---- epilogue: ll for t = 127 (duty r = 7) ----
  if (r == 7) {
    const int tl = Nn - 1;
    const int pp = tl & 1;   // = 1
    float term = 0.0f;
    if (tid < tl) {
      float lsum = b2v;
      const unsigned* Lp = LOGPb + pp*1024;
      #pragma unroll
      for (int rr = 0; rr < 8; ++rr)
        lsum += __uint_as_float(ald32(Lp + rr*Nn + tid));
      const int w = tid >> 5;
      const unsigned av_ = ANCW[pp*8 + w] | ANCW[pp*8 + 4 + w];
      const float anc = (float)((av_ >> (tid & 31)) & 1u);
      float q = sigm(lsum) * (1.0f - 0.5f*anc);
      q = fminf(fmaxf(q, 1e-6f), 1.0f - 1e-6f);
      const unsigned rb = (RBIT[pp*4 + w] >> (tid & 31)) & 1u;
      term = rb ? logf(q) : log1pf(-q);
    }
    if (wv < 2) {
      #pragma unroll
      for (int off = 32; off; off >>= 1) term += __shfl_down(term, off);
      if (lane == 0) atomicAdd(&out[Bz*Nn*Nn + b], term);
    }
  }
}

extern "C" void kernel_launch(void* const* d_in, const int* in_sizes, int n_in,
                              void* d_out, int out_size, void* d_ws, size_t ws_size,
                              hipStream_t stream)
{
  const float* z  = (const float*)d_in[0];
  const int*   tg = (const int*)  d_in[1];
  const float* Wi = (const float*)d_in[2];
  const float* bi = (const float*)d_in[3];
  const float* Wx = (const float*)d_in[4];
  const float* Wh = (const float*)d_in[5];
  const float* bx = (const float*)d_in[6];
  const float* bh = (const float*)d_in[7];
  const float* W1 = (const float*)d_in[8];
  const float* b1 = (const float*)d_in[9];
  const float* W2 = (const float*)d_in[10];
  const float* b2 = (const float*)d_in[11];
  float* out = (float*)d_out;
  float* ws  = (float*)d_ws;

  hipFuncSetAttribute((const void*)decoder_main,
                      hipFuncAttributeMaxDynamicSharedMemorySize, SMEM_SZ);

  hipLaunchKernelGGL(prep_init, dim3(512), dim3(256), 0, stream, tg, Wx, Wh, W1, ws, out);
  hipLaunchKernelGGL(prep_batch, dim3(Bz), dim3(256), 0, stream, z, Wi, bi, Wh, bh, W1, ws);

  void* args[] = { (void*)&tg, (void*)&bx, (void*)&bh, (void*)&b1,
                   (void*)&W2, (void*)&b2, (void*)&ws, (void*)&out };
  hipLaunchCooperativeKernel((void*)decoder_main, dim3(256), dim3(NT),
                             args, SMEM_SZ, stream);
}